// Round 6
// baseline (927.244 us; speedup 1.0000x reference)
//
#include <hip/hip_runtime.h>

// loraLinearAttention on MI355X — fp32, LoRA folded into effective weights,
// linear attention collapsed to per-(b,h) 32x32 context and per-batch 128x128
// merged output matrix M_b = w_out @ blockdiag(ctx_h^T) * SCALE.
//
// R4->R5: REVERT the __launch_bounds__(256,4) min-waves force. It capped
// VGPRs at 64 (< the ~84 this kernel needs) -> scratch spills -> 638 MB of
// spill traffic/dispatch, VALUBusy 6%, 616 us. Natural VGPR (~84..128) gives
// 4 waves/SIMD anyway with the 32 KB LDS buffer. Keep NCHUNK=16, aliased
// single buffer, exp-in-regs, vT pitch-36 from R4.

#define SCALING 0.25f
#define SCALE   0.17677669529663687f   /* 32^-0.5 */
#define NCHUNK  16
#define VOFF    2080                   /* float offset of vT inside buf */

__global__ __launch_bounds__(256) void fold_kernel(
    const float* __restrict__ w_qkv,
    const float* __restrict__ wA_q, const float* __restrict__ bA_q,
    const float* __restrict__ wB_q, const float* __restrict__ bB_q,
    const float* __restrict__ wA_k, const float* __restrict__ bA_k,
    const float* __restrict__ wB_k, const float* __restrict__ bB_k,
    const float* __restrict__ wA_v, const float* __restrict__ bA_v,
    const float* __restrict__ wB_v, const float* __restrict__ bB_v,
    float* __restrict__ Wt, float* __restrict__ beff)
{
    int idx = blockIdx.x * 256 + threadIdx.x;   // 49152 total
    int m = idx >> 14;
    int c = (idx >> 7) & 127;
    int o = idx & 127;
    const float* wA = (m == 0) ? wA_q : (m == 1) ? wA_k : wA_v;
    const float* wB = (m == 0) ? wB_q : (m == 1) ? wB_k : wB_v;
    float s = w_qkv[(m * 128 + o) * 128 + c];
    #pragma unroll
    for (int r = 0; r < 4; ++r)
        s += SCALING * wB[o * 4 + r] * wA[r * 128 + c];
    Wt[m * 16384 + c * 128 + o] = s;           // transposed [c][o]

    if (blockIdx.x == 0 && threadIdx.x < 384) {
        int mm = threadIdx.x >> 7, oo = threadIdx.x & 127;
        const float* wBm = (mm == 0) ? wB_q : (mm == 1) ? wB_k : wB_v;
        const float* bAm = (mm == 0) ? bA_q : (mm == 1) ? bA_k : bA_v;
        const float* bBm = (mm == 0) ? bB_q : (mm == 1) ? bB_k : bB_v;
        float bb = bBm[oo];
        #pragma unroll
        for (int r = 0; r < 4; ++r) bb += wBm[oo * 4 + r] * bAm[r];
        beff[mm * 128 + oo] = SCALING * bb;
    }
}

// grid (chunk=16, h=4, b=16) = 1024 blocks, 256 threads, 32KB LDS.
// Each block: 256 pixels in 4 tiles of 64.
// buf layout: phase 1 = x tile [128][64]; phase 2 = exp(k) [32][65] @0,
// vT [64 px][36] @VOFF (only cols 0..31 used; pitch 36 for b128 alignment).
__global__ __launch_bounds__(256) void ctx_partial_kernel(
    const float* __restrict__ x, const float* __restrict__ Wt,
    const float* __restrict__ beff, float* __restrict__ part)
{
    __shared__ float buf[8192];          // exactly 32 KB
    const int t = threadIdx.x;
    const int chunk = blockIdx.x, h = blockIdx.y, b = blockIdx.z;
    const int n = t & 63;
    const int og = __builtin_amdgcn_readfirstlane(t >> 6);  // wave id 0..3
    const int is_v = og >> 1;            // waves 0,1 -> k; 2,3 -> v
    const int r0 = (og & 1) * 16;
    const float* Wm = Wt + (1 + is_v) * 16384 + h * 32 + r0;
    const float* bm = beff + (1 + is_v) * 128 + h * 32 + r0;
    const float* xb = x + (size_t)b * (128 * 4096);
    const int d = t & 31;                // ctx-phase row
    const int g = t >> 5;                // ctx-phase e-quad 0..7

    float cacc[4] = {0.f, 0.f, 0.f, 0.f};
    float lpart = 0.f;                   // every thread sums its d; g==0 writes

    for (int tt = 0; tt < 4; ++tt) {
        const int n0 = chunk * 256 + tt * 64;
        __syncthreads();                 // prev-tile ctx reads of buf done
        #pragma unroll
        for (int i = 0; i < 8; ++i) {    // x tile [128][64] as float4
            int idx4 = i * 256 + t;
            int c = idx4 >> 4, q4 = idx4 & 15;
            *(float4*)(&buf[c * 64 + q4 * 4]) =
                *(const float4*)(xb + (size_t)c * 4096 + n0 + q4 * 4);
        }
        __syncthreads();
        // k/v matvec: 16 rows per thread, wave-uniform scalar W loads
        float acc[16];
        #pragma unroll
        for (int i = 0; i < 16; ++i) acc[i] = bm[i];
        for (int c = 0; c < 128; ++c) {
            float xv = buf[c * 64 + n];
            const float* wr = Wm + c * 128;
            #pragma unroll
            for (int i = 0; i < 16; ++i) acc[i] = fmaf(wr[i], xv, acc[i]);
        }
        __syncthreads();                 // all matvec reads of x done
        if (!is_v) {                     // k-waves: exp in regs, store [d][65]
            #pragma unroll
            for (int i = 0; i < 16; ++i)
                buf[(r0 + i) * 65 + n] = __expf(acc[i]);
        } else {                         // v-waves: store transposed [n][36]
            #pragma unroll
            for (int i4 = 0; i4 < 4; ++i4) {
                float4 vv = {acc[i4*4], acc[i4*4+1], acc[i4*4+2], acc[i4*4+3]};
                *(float4*)(&buf[VOFF + n * 36 + r0 + i4 * 4]) = vv;
            }
        }
        __syncthreads();
        // ctx accumulate: thread owns (d, e = g*4..g*4+3); p broadcast, v b128
        for (int nn = 0; nn < 64; ++nn) {
            float p = buf[d * 65 + nn];
            float4 vv = *(const float4*)(&buf[VOFF + nn * 36 + g * 4]);
            cacc[0] = fmaf(p, vv.x, cacc[0]);
            cacc[1] = fmaf(p, vv.y, cacc[1]);
            cacc[2] = fmaf(p, vv.z, cacc[2]);
            cacc[3] = fmaf(p, vv.w, cacc[3]);
            lpart += p;                  // all threads; only g==0 result used
        }
    }
    float* pout = part + (size_t)((b * 4 + h) * NCHUNK + chunk) * 1056;
    if (g == 0) pout[1024 + d] = lpart;
    #pragma unroll
    for (int j = 0; j < 4; ++j) pout[d * 32 + g * 4 + j] = cacc[j];
}

// grid (16 = batch), 256 threads
__global__ __launch_bounds__(256) void combine_m_kernel(
    const float* __restrict__ part, const float* __restrict__ w_out,
    float* __restrict__ Mt)
{
    __shared__ float ctx[4096];        // [h][d][e]
    __shared__ float linv[128];
    __shared__ float wt[128 * 129];    // w_out^T, padded
    const int t = threadIdx.x;
    const int b = blockIdx.x;
    const float* pb = part + (size_t)b * 4 * NCHUNK * 1056;

    if (t < 128) {
        int h = t >> 5, d = t & 31;
        float l = 0.f;
        for (int ch = 0; ch < NCHUNK; ++ch)
            l += pb[(h * NCHUNK + ch) * 1056 + 1024 + d];
        linv[t] = 1.0f / (l * 4096.0f);   // folds the v/n division
    }
    for (int i = 0; i < 64; ++i) {        // stage w_out transposed
        int idx = i * 256 + t;
        int o = idx >> 7, c = idx & 127;
        wt[c * 129 + o] = w_out[idx];
    }
    __syncthreads();
    for (int i = 0; i < 16; ++i) {        // context = sum(partials) * linv
        int idx = i * 256 + t;
        int h = idx >> 10, d = (idx >> 5) & 31, e = idx & 31;
        float s = 0.f;
        for (int ch = 0; ch < NCHUNK; ++ch)
            s += pb[(h * NCHUNK + ch) * 1056 + d * 32 + e];
        ctx[idx] = s * linv[h * 32 + d];
    }
    __syncthreads();
    for (int i = 0; i < 64; ++i) {        // M_b^T[j][o] = SCALE * sum_e wt[he][o]*ctx[h][d][e]
        int idx = i * 256 + t;
        int j = idx >> 7, o = idx & 127;
        int h = j >> 5, d = j & 31;
        float s = 0.f;
        #pragma unroll
        for (int e = 0; e < 32; ++e)
            s = fmaf(wt[(h * 32 + e) * 129 + o], ctx[(h * 32 + d) * 32 + e], s);
        Mt[(size_t)b * 16384 + j * 128 + o] = s * SCALE;
    }
}

// grid (tile=64, b=16), 256 threads, 32KB LDS; 64 pixels per block.
// buf = x tile during q matvec, then qs (softmaxed q) for the M matvec.
__global__ __launch_bounds__(256) void pass_b_kernel(
    const float* __restrict__ x, const float* __restrict__ Wt,
    const float* __restrict__ beff, const float* __restrict__ Mt,
    const float* __restrict__ b_out, float* __restrict__ out)
{
    __shared__ float buf[8192];          // exactly 32 KB
    const int t = threadIdx.x;
    const int tile = blockIdx.x, b = blockIdx.y;
    const int n = t & 63;
    const int h = __builtin_amdgcn_readfirstlane(t >> 6);  // wave id = head
    const int n0 = tile * 64;
    const float* xb = x + (size_t)b * (128 * 4096);

    #pragma unroll
    for (int i = 0; i < 8; ++i) {
        int idx4 = i * 256 + t;
        int c = idx4 >> 4, q4 = idx4 & 15;
        *(float4*)(&buf[c * 64 + q4 * 4]) =
            *(const float4*)(xb + (size_t)c * 4096 + n0 + q4 * 4);
    }
    __syncthreads();
    // q logits: 32 rows o = h*32+i
    float acc[32];
    const float* Wq = Wt + h * 32;
    const float* bq = beff + h * 32;
    #pragma unroll
    for (int i = 0; i < 32; ++i) acc[i] = bq[i];
    for (int c = 0; c < 128; ++c) {
        float xv = buf[c * 64 + n];
        const float* wr = Wq + c * 128;
        #pragma unroll
        for (int i = 0; i < 32; ++i) acc[i] = fmaf(wr[i], xv, acc[i]);
    }
    // softmax over the 32 head channels (in registers)
    float m = acc[0];
    #pragma unroll
    for (int i = 1; i < 32; ++i) m = fmaxf(m, acc[i]);
    float s = 0.f;
    #pragma unroll
    for (int i = 0; i < 32; ++i) { acc[i] = __expf(acc[i] - m); s += acc[i]; }
    float inv = 1.0f / s;
    __syncthreads();                     // all q-matvec reads of x done
    #pragma unroll
    for (int i = 0; i < 32; ++i) buf[(h * 32 + i) * 64 + n] = acc[i] * inv;
    __syncthreads();
    // out = M_b @ qs (+ b_out)
    float oacc[32];
    const float* Mb = Mt + (size_t)b * 16384 + h * 32;
    const float* bo = b_out + h * 32;
    #pragma unroll
    for (int i = 0; i < 32; ++i) oacc[i] = bo[i];
    for (int j = 0; j < 128; ++j) {
        float qv = buf[j * 64 + n];
        const float* mr = Mb + j * 128;
        #pragma unroll
        for (int i = 0; i < 32; ++i) oacc[i] = fmaf(mr[i], qv, oacc[i]);
    }
    float* ob = out + (size_t)b * (128 * 4096) + n0;
    #pragma unroll
    for (int i = 0; i < 32; ++i) ob[(h * 32 + i) * 4096 + n] = oacc[i];
}

extern "C" void kernel_launch(void* const* d_in, const int* in_sizes, int n_in,
                              void* d_out, int out_size, void* d_ws, size_t ws_size,
                              hipStream_t stream) {
    const float* x     = (const float*)d_in[0];
    const float* w_qkv = (const float*)d_in[1];
    const float* wA_q  = (const float*)d_in[2];
    const float* bA_q  = (const float*)d_in[3];
    const float* wB_q  = (const float*)d_in[4];
    const float* bB_q  = (const float*)d_in[5];
    const float* wA_k  = (const float*)d_in[6];
    const float* bA_k  = (const float*)d_in[7];
    const float* wB_k  = (const float*)d_in[8];
    const float* bB_k  = (const float*)d_in[9];
    const float* wA_v  = (const float*)d_in[10];
    const float* bA_v  = (const float*)d_in[11];
    const float* wB_v  = (const float*)d_in[12];
    const float* bB_v  = (const float*)d_in[13];
    const float* w_out = (const float*)d_in[14];
    const float* b_out = (const float*)d_in[15];
    float* out = (float*)d_out;

    float* ws = (float*)d_ws;
    float* Wt   = ws;                          // 3 * 16384
    float* beff = ws + 49152;                  // 3 * 128
    float* part = ws + 49536;                  // 16*4*16 * 1056 = 1081344
    float* Mt   = ws + 49536 + 1081344;        // 16 * 16384

    fold_kernel<<<192, 256, 0, stream>>>(w_qkv,
        wA_q, bA_q, wB_q, bB_q, wA_k, bA_k, wB_k, bB_k, wA_v, bA_v, wB_v, bB_v,
        Wt, beff);
    ctx_partial_kernel<<<dim3(NCHUNK, 4, 16), 256, 0, stream>>>(x, Wt, beff, part);
    combine_m_kernel<<<16, 256, 0, stream>>>(part, w_out, Mt);
    pass_b_kernel<<<dim3(64, 16), 256, 0, stream>>>(x, Wt, beff, Mt, b_out, out);
}

// Round 7
// 189.403 us; speedup vs baseline: 4.8956x; 4.8956x over previous
//
#include <hip/hip_runtime.h>

// loraLinearAttention on MI355X — fp32, LoRA folded into effective weights,
// linear attention collapsed to per-(b,h) 32x32 context and per-batch 128x128
// merged output matrix M_b = w_out @ blockdiag(ctx_h^T) * SCALE.
//
// R6->R7: ctx_partial reverted to the R3 body (measured: VGPR 84, no spill,
// VALUBusy 36%). The R4/R5 restructure (aliased buf + divergent exp/transpose
// + float4 ctx loop) spilled at ANY register budget (R4: capped 64 -> 638 MB
// spill traffic; R5: uncapped -> 256 VGPR + 1.27 GB traffic, 880 us).
// Controlled deltas vs R3: NCHUNK 8->16 (3 blocks/CU by LDS, was grid-limited
// to 2), and #pragma unroll 1 on the 4-iter tile loop to forbid cross-barrier
// unroll/pipelining. pass_b kept from R5 (aliased 32KB buf, ~40 us measured
// by subtraction).

#define SCALING 0.25f
#define SCALE   0.17677669529663687f   /* 32^-0.5 */
#define NCHUNK  16

__global__ __launch_bounds__(256) void fold_kernel(
    const float* __restrict__ w_qkv,
    const float* __restrict__ wA_q, const float* __restrict__ bA_q,
    const float* __restrict__ wB_q, const float* __restrict__ bB_q,
    const float* __restrict__ wA_k, const float* __restrict__ bA_k,
    const float* __restrict__ wB_k, const float* __restrict__ bB_k,
    const float* __restrict__ wA_v, const float* __restrict__ bA_v,
    const float* __restrict__ wB_v, const float* __restrict__ bB_v,
    float* __restrict__ Wt, float* __restrict__ beff)
{
    int idx = blockIdx.x * 256 + threadIdx.x;   // 49152 total
    int m = idx >> 14;
    int c = (idx >> 7) & 127;
    int o = idx & 127;
    const float* wA = (m == 0) ? wA_q : (m == 1) ? wA_k : wA_v;
    const float* wB = (m == 0) ? wB_q : (m == 1) ? wB_k : wB_v;
    float s = w_qkv[(m * 128 + o) * 128 + c];
    #pragma unroll
    for (int r = 0; r < 4; ++r)
        s += SCALING * wB[o * 4 + r] * wA[r * 128 + c];
    Wt[m * 16384 + c * 128 + o] = s;           // transposed [c][o]

    if (blockIdx.x == 0 && threadIdx.x < 384) {
        int mm = threadIdx.x >> 7, oo = threadIdx.x & 127;
        const float* wBm = (mm == 0) ? wB_q : (mm == 1) ? wB_k : wB_v;
        const float* bAm = (mm == 0) ? bA_q : (mm == 1) ? bA_k : bA_v;
        const float* bBm = (mm == 0) ? bB_q : (mm == 1) ? bB_k : bB_v;
        float bb = bBm[oo];
        #pragma unroll
        for (int r = 0; r < 4; ++r) bb += wBm[oo * 4 + r] * bAm[r];
        beff[mm * 128 + oo] = SCALING * bb;
    }
}

// grid (chunk=16, h=4, b=16) = 1024 blocks, 256 threads, ~50.4KB LDS
// -> 3 blocks/CU. Each block: 256 pixels in 4 tiles of 64. R3 body.
__global__ __launch_bounds__(256) void ctx_partial_kernel(
    const float* __restrict__ x, const float* __restrict__ Wt,
    const float* __restrict__ beff, float* __restrict__ part)
{
    __shared__ float x_t[128 * 64];
    __shared__ float kv_t[2][32 * 65];   // pitch 65: column reads conflict-free
    __shared__ float lsum[8][32];
    const int t = threadIdx.x;
    const int chunk = blockIdx.x, h = blockIdx.y, b = blockIdx.z;
    const int n = t & 63;
    const int og = __builtin_amdgcn_readfirstlane(t >> 6);  // wave id 0..3
    const int is_v = og >> 1;            // waves 0,1 -> k; 2,3 -> v
    const int r0 = (og & 1) * 16;
    const float* Wm = Wt + (1 + is_v) * 16384 + h * 32 + r0;
    const float* bm = beff + (1 + is_v) * 128 + h * 32 + r0;
    const float* xb = x + (size_t)b * (128 * 4096);
    const int d = t & 31;                // row for exp/ctx phases
    const int g = t >> 5;                // 0..7

    float cacc[4] = {0.f, 0.f, 0.f, 0.f};
    float lpart = 0.f;

    #pragma unroll 1
    for (int tt = 0; tt < 4; ++tt) {
        const int n0 = chunk * 256 + tt * 64;
        __syncthreads();
        #pragma unroll
        for (int i = 0; i < 8; ++i) {     // load x tile [128][64] as float4
            int idx4 = i * 256 + t;
            int c = idx4 >> 4, q4 = idx4 & 15;
            float4 v = *(const float4*)(xb + (size_t)c * 4096 + n0 + q4 * 4);
            *(float4*)(&x_t[c * 64 + q4 * 4]) = v;
        }
        __syncthreads();
        // k/v matvec: 16 rows per thread, W via wave-uniform scalar loads
        float acc[16];
        #pragma unroll
        for (int i = 0; i < 16; ++i) acc[i] = bm[i];
        for (int c = 0; c < 128; ++c) {
            float xv = x_t[c * 64 + n];
            const float* wr = Wm + c * 128;
            #pragma unroll
            for (int i = 0; i < 16; ++i) acc[i] = fmaf(wr[i], xv, acc[i]);
        }
        #pragma unroll
        for (int i = 0; i < 16; ++i) kv_t[is_v][(r0 + i) * 65 + n] = acc[i];
        __syncthreads();
        // exp(k) in place (max-free softmax: |k| bounded ~4), row partial sums
        float lp = 0.f;
        #pragma unroll
        for (int j = 0; j < 8; ++j) {
            int nn = g * 8 + j;
            float p = __expf(kv_t[0][d * 65 + nn]);
            kv_t[0][d * 65 + nn] = p;
            lp += p;
        }
        lpart += lp;
        __syncthreads();
        // context accumulate: thread owns (d, e = g*4+j), j<4
        for (int nn = 0; nn < 64; ++nn) {
            float p = kv_t[0][d * 65 + nn];
            #pragma unroll
            for (int j = 0; j < 4; ++j)
                cacc[j] = fmaf(p, kv_t[1][(g * 4 + j) * 65 + nn], cacc[j]);
        }
    }
    lsum[g][d] = lpart;
    __syncthreads();
    float* pout = part + (size_t)((b * 4 + h) * NCHUNK + chunk) * 1056;
    if (t < 32) {
        float l = 0.f;
        #pragma unroll
        for (int gg = 0; gg < 8; ++gg) l += lsum[gg][t];
        pout[1024 + t] = l;
    }
    #pragma unroll
    for (int j = 0; j < 4; ++j) pout[d * 32 + g * 4 + j] = cacc[j];
}

// grid (16 = batch), 256 threads
__global__ __launch_bounds__(256) void combine_m_kernel(
    const float* __restrict__ part, const float* __restrict__ w_out,
    float* __restrict__ Mt)
{
    __shared__ float ctx[4096];        // [h][d][e]
    __shared__ float linv[128];
    __shared__ float wt[128 * 129];    // w_out^T, padded
    const int t = threadIdx.x;
    const int b = blockIdx.x;
    const float* pb = part + (size_t)b * 4 * NCHUNK * 1056;

    if (t < 128) {
        int h = t >> 5, d = t & 31;
        float l = 0.f;
        for (int ch = 0; ch < NCHUNK; ++ch)
            l += pb[(h * NCHUNK + ch) * 1056 + 1024 + d];
        linv[t] = 1.0f / (l * 4096.0f);   // folds the v/n division
    }
    for (int i = 0; i < 64; ++i) {        // stage w_out transposed
        int idx = i * 256 + t;
        int o = idx >> 7, c = idx & 127;
        wt[c * 129 + o] = w_out[idx];
    }
    __syncthreads();
    for (int i = 0; i < 16; ++i) {        // context = sum(partials) * linv
        int idx = i * 256 + t;
        int h = idx >> 10, d = (idx >> 5) & 31, e = idx & 31;
        float s = 0.f;
        for (int ch = 0; ch < NCHUNK; ++ch)
            s += pb[(h * NCHUNK + ch) * 1056 + d * 32 + e];
        ctx[idx] = s * linv[h * 32 + d];
    }
    __syncthreads();
    for (int i = 0; i < 64; ++i) {        // M_b^T[j][o] = SCALE * sum_e wt[he][o]*ctx[h][d][e]
        int idx = i * 256 + t;
        int j = idx >> 7, o = idx & 127;
        int h = j >> 5, d = j & 31;
        float s = 0.f;
        #pragma unroll
        for (int e = 0; e < 32; ++e)
            s = fmaf(wt[(h * 32 + e) * 129 + o], ctx[(h * 32 + d) * 32 + e], s);
        Mt[(size_t)b * 16384 + j * 128 + o] = s * SCALE;
    }
}

// grid (tile=64, b=16), 256 threads, 32KB LDS; 64 pixels per block.
// buf = x tile during q matvec, then qs (softmaxed q) for the M matvec.
__global__ __launch_bounds__(256) void pass_b_kernel(
    const float* __restrict__ x, const float* __restrict__ Wt,
    const float* __restrict__ beff, const float* __restrict__ Mt,
    const float* __restrict__ b_out, float* __restrict__ out)
{
    __shared__ float buf[8192];          // exactly 32 KB
    const int t = threadIdx.x;
    const int tile = blockIdx.x, b = blockIdx.y;
    const int n = t & 63;
    const int h = __builtin_amdgcn_readfirstlane(t >> 6);  // wave id = head
    const int n0 = tile * 64;
    const float* xb = x + (size_t)b * (128 * 4096);

    #pragma unroll
    for (int i = 0; i < 8; ++i) {
        int idx4 = i * 256 + t;
        int c = idx4 >> 4, q4 = idx4 & 15;
        *(float4*)(&buf[c * 64 + q4 * 4]) =
            *(const float4*)(xb + (size_t)c * 4096 + n0 + q4 * 4);
    }
    __syncthreads();
    // q logits: 32 rows o = h*32+i
    float acc[32];
    const float* Wq = Wt + h * 32;
    const float* bq = beff + h * 32;
    #pragma unroll
    for (int i = 0; i < 32; ++i) acc[i] = bq[i];
    for (int c = 0; c < 128; ++c) {
        float xv = buf[c * 64 + n];
        const float* wr = Wq + c * 128;
        #pragma unroll
        for (int i = 0; i < 32; ++i) acc[i] = fmaf(wr[i], xv, acc[i]);
    }
    // softmax over the 32 head channels (in registers)
    float m = acc[0];
    #pragma unroll
    for (int i = 1; i < 32; ++i) m = fmaxf(m, acc[i]);
    float s = 0.f;
    #pragma unroll
    for (int i = 0; i < 32; ++i) { acc[i] = __expf(acc[i] - m); s += acc[i]; }
    float inv = 1.0f / s;
    __syncthreads();                     // all q-matvec reads of x done
    #pragma unroll
    for (int i = 0; i < 32; ++i) buf[(h * 32 + i) * 64 + n] = acc[i] * inv;
    __syncthreads();
    // out = M_b @ qs (+ b_out)
    float oacc[32];
    const float* Mb = Mt + (size_t)b * 16384 + h * 32;
    const float* bo = b_out + h * 32;
    #pragma unroll
    for (int i = 0; i < 32; ++i) oacc[i] = bo[i];
    for (int j = 0; j < 128; ++j) {
        float qv = buf[j * 64 + n];
        const float* mr = Mb + j * 128;
        #pragma unroll
        for (int i = 0; i < 32; ++i) oacc[i] = fmaf(mr[i], qv, oacc[i]);
    }
    float* ob = out + (size_t)b * (128 * 4096) + n0;
    #pragma unroll
    for (int i = 0; i < 32; ++i) ob[(h * 32 + i) * 4096 + n] = oacc[i];
}

extern "C" void kernel_launch(void* const* d_in, const int* in_sizes, int n_in,
                              void* d_out, int out_size, void* d_ws, size_t ws_size,
                              hipStream_t stream) {
    const float* x     = (const float*)d_in[0];
    const float* w_qkv = (const float*)d_in[1];
    const float* wA_q  = (const float*)d_in[2];
    const float* bA_q  = (const float*)d_in[3];
    const float* wB_q  = (const float*)d_in[4];
    const float* bB_q  = (const float*)d_in[5];
    const float* wA_k  = (const float*)d_in[6];
    const float* bA_k  = (const float*)d_in[7];
    const float* wB_k  = (const float*)d_in[8];
    const float* bB_k  = (const float*)d_in[9];
    const float* wA_v  = (const float*)d_in[10];
    const float* bA_v  = (const float*)d_in[11];
    const float* wB_v  = (const float*)d_in[12];
    const float* bB_v  = (const float*)d_in[13];
    const float* w_out = (const float*)d_in[14];
    const float* b_out = (const float*)d_in[15];
    float* out = (float*)d_out;

    float* ws = (float*)d_ws;
    float* Wt   = ws;                          // 3 * 16384
    float* beff = ws + 49152;                  // 3 * 128
    float* part = ws + 49536;                  // 16*4*16 * 1056 = 1081344
    float* Mt   = ws + 49536 + 1081344;        // 16 * 16384

    fold_kernel<<<192, 256, 0, stream>>>(w_qkv,
        wA_q, bA_q, wB_q, bB_q, wA_k, bA_k, wB_k, bB_k, wA_v, bA_v, wB_v, bB_v,
        Wt, beff);
    ctx_partial_kernel<<<dim3(NCHUNK, 4, 16), 256, 0, stream>>>(x, Wt, beff, part);
    combine_m_kernel<<<16, 256, 0, stream>>>(part, w_out, Mt);
    pass_b_kernel<<<dim3(64, 16), 256, 0, stream>>>(x, Wt, beff, Mt, b_out, out);
}

// Round 8
// 184.669 us; speedup vs baseline: 5.0211x; 1.0256x over previous
//
#include <hip/hip_runtime.h>

// loraLinearAttention on MI355X — fp32, LoRA folded into effective weights,
// linear attention collapsed to per-(b,h) 32x32 context and per-batch 128x128
// merged output matrix M_b = w_out @ blockdiag(ctx_h^T) * SCALE.
//
// R7->R8: ctx_partial LDS 49.5 KB -> 33.9 KB by streaming x in two c-halves
// ([64][64] tile instead of [128][64]). R7 counters showed 3 blocks/CU LDS
// capacity vs 1024-block grid = 4/CU of work -> TWO dispatch rounds (avg 2
// blocks/CU, occupancy 22.7%, same as R3). At 33.9 KB: 4 blocks/CU, one
// round, 16 waves/CU. Inner body otherwise the measured-good R3 structure
// (VGPR 84, zero spill). pass_b untouched (~fp32 VALU floor already).

#define SCALING 0.25f
#define SCALE   0.17677669529663687f   /* 32^-0.5 */
#define NCHUNK  16

__global__ __launch_bounds__(256) void fold_kernel(
    const float* __restrict__ w_qkv,
    const float* __restrict__ wA_q, const float* __restrict__ bA_q,
    const float* __restrict__ wB_q, const float* __restrict__ bB_q,
    const float* __restrict__ wA_k, const float* __restrict__ bA_k,
    const float* __restrict__ wB_k, const float* __restrict__ bB_k,
    const float* __restrict__ wA_v, const float* __restrict__ bA_v,
    const float* __restrict__ wB_v, const float* __restrict__ bB_v,
    float* __restrict__ Wt, float* __restrict__ beff)
{
    int idx = blockIdx.x * 256 + threadIdx.x;   // 49152 total
    int m = idx >> 14;
    int c = (idx >> 7) & 127;
    int o = idx & 127;
    const float* wA = (m == 0) ? wA_q : (m == 1) ? wA_k : wA_v;
    const float* wB = (m == 0) ? wB_q : (m == 1) ? wB_k : wB_v;
    float s = w_qkv[(m * 128 + o) * 128 + c];
    #pragma unroll
    for (int r = 0; r < 4; ++r)
        s += SCALING * wB[o * 4 + r] * wA[r * 128 + c];
    Wt[m * 16384 + c * 128 + o] = s;           // transposed [c][o]

    if (blockIdx.x == 0 && threadIdx.x < 384) {
        int mm = threadIdx.x >> 7, oo = threadIdx.x & 127;
        const float* wBm = (mm == 0) ? wB_q : (mm == 1) ? wB_k : wB_v;
        const float* bAm = (mm == 0) ? bA_q : (mm == 1) ? bA_k : bA_v;
        const float* bBm = (mm == 0) ? bB_q : (mm == 1) ? bB_k : bB_v;
        float bb = bBm[oo];
        #pragma unroll
        for (int r = 0; r < 4; ++r) bb += wBm[oo * 4 + r] * bAm[r];
        beff[mm * 128 + oo] = SCALING * bb;
    }
}

// grid (chunk=16, h=4, b=16) = 1024 blocks, 256 threads, ~33.9KB LDS
// -> 4 blocks/CU, one dispatch round. Each block: 256 pixels in 4 tiles
// of 64; x streamed in two 64-channel halves per tile.
__global__ __launch_bounds__(256) void ctx_partial_kernel(
    const float* __restrict__ x, const float* __restrict__ Wt,
    const float* __restrict__ beff, float* __restrict__ part)
{
    __shared__ float x_t[64 * 64];       // one c-half of the x tile (16 KB)
    __shared__ float kv_t[2][32 * 65];   // pitch 65: column reads conflict-free
    __shared__ float lsum[8][32];
    const int t = threadIdx.x;
    const int chunk = blockIdx.x, h = blockIdx.y, b = blockIdx.z;
    const int n = t & 63;
    const int og = __builtin_amdgcn_readfirstlane(t >> 6);  // wave id 0..3
    const int is_v = og >> 1;            // waves 0,1 -> k; 2,3 -> v
    const int r0 = (og & 1) * 16;
    const float* Wm = Wt + (1 + is_v) * 16384 + h * 32 + r0;
    const float* bm = beff + (1 + is_v) * 128 + h * 32 + r0;
    const float* xb = x + (size_t)b * (128 * 4096);
    const int d = t & 31;                // row for exp/ctx phases
    const int g = t >> 5;                // 0..7

    float cacc[4] = {0.f, 0.f, 0.f, 0.f};
    float lpart = 0.f;

    #pragma unroll 1
    for (int tt = 0; tt < 4; ++tt) {
        const int n0 = chunk * 256 + tt * 64;
        float acc[16];
        #pragma unroll
        for (int i = 0; i < 16; ++i) acc[i] = bm[i];
        #pragma unroll 1
        for (int ch = 0; ch < 2; ++ch) {
            __syncthreads();             // prev reads of x_t (or kv phase) done
            #pragma unroll
            for (int i = 0; i < 4; ++i) {   // x half-tile [64][64] as float4
                int idx4 = i * 256 + t;
                int c = idx4 >> 4, q4 = idx4 & 15;
                float4 v = *(const float4*)(xb + (size_t)(ch * 64 + c) * 4096
                                            + n0 + q4 * 4);
                *(float4*)(&x_t[c * 64 + q4 * 4]) = v;
            }
            __syncthreads();
            const float* Wc = Wm + (ch * 64) * 128;
            for (int c = 0; c < 64; ++c) {
                float xv = x_t[c * 64 + n];
                const float* wr = Wc + c * 128;
                #pragma unroll
                for (int i = 0; i < 16; ++i) acc[i] = fmaf(wr[i], xv, acc[i]);
            }
        }
        __syncthreads();                 // all matvec reads of x_t done
        #pragma unroll
        for (int i = 0; i < 16; ++i) kv_t[is_v][(r0 + i) * 65 + n] = acc[i];
        __syncthreads();
        // exp(k) in place (max-free softmax: |k| bounded ~4), row partial sums
        float lp = 0.f;
        #pragma unroll
        for (int j = 0; j < 8; ++j) {
            int nn = g * 8 + j;
            float p = __expf(kv_t[0][d * 65 + nn]);
            kv_t[0][d * 65 + nn] = p;
            lp += p;
        }
        lpart += lp;
        __syncthreads();
        // context accumulate: thread owns (d, e = g*4+j), j<4
        for (int nn = 0; nn < 64; ++nn) {
            float p = kv_t[0][d * 65 + nn];
            #pragma unroll
            for (int j = 0; j < 4; ++j)
                cacc[j] = fmaf(p, kv_t[1][(g * 4 + j) * 65 + nn], cacc[j]);
        }
    }
    lsum[g][d] = lpart;
    __syncthreads();
    float* pout = part + (size_t)((b * 4 + h) * NCHUNK + chunk) * 1056;
    if (t < 32) {
        float l = 0.f;
        #pragma unroll
        for (int gg = 0; gg < 8; ++gg) l += lsum[gg][t];
        pout[1024 + t] = l;
    }
    #pragma unroll
    for (int j = 0; j < 4; ++j) pout[d * 32 + g * 4 + j] = cacc[j];
}

// grid (16 = batch), 256 threads
__global__ __launch_bounds__(256) void combine_m_kernel(
    const float* __restrict__ part, const float* __restrict__ w_out,
    float* __restrict__ Mt)
{
    __shared__ float ctx[4096];        // [h][d][e]
    __shared__ float linv[128];
    __shared__ float wt[128 * 129];    // w_out^T, padded
    const int t = threadIdx.x;
    const int b = blockIdx.x;
    const float* pb = part + (size_t)b * 4 * NCHUNK * 1056;

    if (t < 128) {
        int h = t >> 5, d = t & 31;
        float l = 0.f;
        for (int ch = 0; ch < NCHUNK; ++ch)
            l += pb[(h * NCHUNK + ch) * 1056 + 1024 + d];
        linv[t] = 1.0f / (l * 4096.0f);   // folds the v/n division
    }
    for (int i = 0; i < 64; ++i) {        // stage w_out transposed
        int idx = i * 256 + t;
        int o = idx >> 7, c = idx & 127;
        wt[c * 129 + o] = w_out[idx];
    }
    __syncthreads();
    for (int i = 0; i < 16; ++i) {        // context = sum(partials) * linv
        int idx = i * 256 + t;
        int h = idx >> 10, d = (idx >> 5) & 31, e = idx & 31;
        float s = 0.f;
        for (int ch = 0; ch < NCHUNK; ++ch)
            s += pb[(h * NCHUNK + ch) * 1056 + d * 32 + e];
        ctx[idx] = s * linv[h * 32 + d];
    }
    __syncthreads();
    for (int i = 0; i < 64; ++i) {        // M_b^T[j][o] = SCALE * sum_e wt[he][o]*ctx[h][d][e]
        int idx = i * 256 + t;
        int j = idx >> 7, o = idx & 127;
        int h = j >> 5, d = j & 31;
        float s = 0.f;
        #pragma unroll
        for (int e = 0; e < 32; ++e)
            s = fmaf(wt[(h * 32 + e) * 129 + o], ctx[(h * 32 + d) * 32 + e], s);
        Mt[(size_t)b * 16384 + j * 128 + o] = s * SCALE;
    }
}

// grid (tile=64, b=16), 256 threads, 32KB LDS; 64 pixels per block.
// buf = x tile during q matvec, then qs (softmaxed q) for the M matvec.
__global__ __launch_bounds__(256) void pass_b_kernel(
    const float* __restrict__ x, const float* __restrict__ Wt,
    const float* __restrict__ beff, const float* __restrict__ Mt,
    const float* __restrict__ b_out, float* __restrict__ out)
{
    __shared__ float buf[8192];          // exactly 32 KB
    const int t = threadIdx.x;
    const int tile = blockIdx.x, b = blockIdx.y;
    const int n = t & 63;
    const int h = __builtin_amdgcn_readfirstlane(t >> 6);  // wave id = head
    const int n0 = tile * 64;
    const float* xb = x + (size_t)b * (128 * 4096);

    #pragma unroll
    for (int i = 0; i < 8; ++i) {
        int idx4 = i * 256 + t;
        int c = idx4 >> 4, q4 = idx4 & 15;
        *(float4*)(&buf[c * 64 + q4 * 4]) =
            *(const float4*)(xb + (size_t)c * 4096 + n0 + q4 * 4);
    }
    __syncthreads();
    // q logits: 32 rows o = h*32+i
    float acc[32];
    const float* Wq = Wt + h * 32;
    const float* bq = beff + h * 32;
    #pragma unroll
    for (int i = 0; i < 32; ++i) acc[i] = bq[i];
    for (int c = 0; c < 128; ++c) {
        float xv = buf[c * 64 + n];
        const float* wr = Wq + c * 128;
        #pragma unroll
        for (int i = 0; i < 32; ++i) acc[i] = fmaf(wr[i], xv, acc[i]);
    }
    // softmax over the 32 head channels (in registers)
    float m = acc[0];
    #pragma unroll
    for (int i = 1; i < 32; ++i) m = fmaxf(m, acc[i]);
    float s = 0.f;
    #pragma unroll
    for (int i = 0; i < 32; ++i) { acc[i] = __expf(acc[i] - m); s += acc[i]; }
    float inv = 1.0f / s;
    __syncthreads();                     // all q-matvec reads of x done
    #pragma unroll
    for (int i = 0; i < 32; ++i) buf[(h * 32 + i) * 64 + n] = acc[i] * inv;
    __syncthreads();
    // out = M_b @ qs (+ b_out)
    float oacc[32];
    const float* Mb = Mt + (size_t)b * 16384 + h * 32;
    const float* bo = b_out + h * 32;
    #pragma unroll
    for (int i = 0; i < 32; ++i) oacc[i] = bo[i];
    for (int j = 0; j < 128; ++j) {
        float qv = buf[j * 64 + n];
        const float* mr = Mb + j * 128;
        #pragma unroll
        for (int i = 0; i < 32; ++i) oacc[i] = fmaf(mr[i], qv, oacc[i]);
    }
    float* ob = out + (size_t)b * (128 * 4096) + n0;
    #pragma unroll
    for (int i = 0; i < 32; ++i) ob[(h * 32 + i) * 4096 + n] = oacc[i];
}

extern "C" void kernel_launch(void* const* d_in, const int* in_sizes, int n_in,
                              void* d_out, int out_size, void* d_ws, size_t ws_size,
                              hipStream_t stream) {
    const float* x     = (const float*)d_in[0];
    const float* w_qkv = (const float*)d_in[1];
    const float* wA_q  = (const float*)d_in[2];
    const float* bA_q  = (const float*)d_in[3];
    const float* wB_q  = (const float*)d_in[4];
    const float* bB_q  = (const float*)d_in[5];
    const float* wA_k  = (const float*)d_in[6];
    const float* bA_k  = (const float*)d_in[7];
    const float* wB_k  = (const float*)d_in[8];
    const float* bB_k  = (const float*)d_in[9];
    const float* wA_v  = (const float*)d_in[10];
    const float* bA_v  = (const float*)d_in[11];
    const float* wB_v  = (const float*)d_in[12];
    const float* bB_v  = (const float*)d_in[13];
    const float* w_out = (const float*)d_in[14];
    const float* b_out = (const float*)d_in[15];
    float* out = (float*)d_out;

    float* ws = (float*)d_ws;
    float* Wt   = ws;                          // 3 * 16384
    float* beff = ws + 49152;                  // 3 * 128
    float* part = ws + 49536;                  // 16*4*16 * 1056 = 1081344
    float* Mt   = ws + 49536 + 1081344;        // 16 * 16384

    fold_kernel<<<192, 256, 0, stream>>>(w_qkv,
        wA_q, bA_q, wB_q, bB_q, wA_k, bA_k, wB_k, bB_k, wA_v, bA_v, wB_v, bB_v,
        Wt, beff);
    ctx_partial_kernel<<<dim3(NCHUNK, 4, 16), 256, 0, stream>>>(x, Wt, beff, part);
    combine_m_kernel<<<16, 256, 0, stream>>>(part, w_out, Mt);
    pass_b_kernel<<<dim3(64, 16), 256, 0, stream>>>(x, Wt, beff, Mt, b_out, out);
}